// Round 7
// baseline (62.854 us; speedup 1.0000x reference)
//
#include <hip/hip_runtime.h>
#include <math.h>

// Problem constants (from reference)
constexpr int Hr = 64;
constexpr int Wr = 2048;
constexpr int Hb = 512;
constexpr int Wb = 512;
constexpr int B  = 4;
constexpr int C  = 64;
constexpr int BC = B * C;            // 256 channels
constexpr int NPIX = Hb * Wb;        // 262144 pixels

constexpr int T   = 16384;           // pixels per block (main kernel)
constexpr int NT  = NPIX / T;        // 16 tiles
constexpr int TPB = 128;             // 2 waves per block

typedef float f32x4 __attribute__((ext_vector_type(4)));

// py = 31.5 exactly -> rows 31,32 with wy = 0.5.
// px in float32 (same arithmetic as R4/R6, absmax 0.0156 << 0.066):
// bilinear interp is continuous in px; the phi-wrap discontinuity is ~0.64 px
// from the nearest sample, so float error cannot cross it. x0 in [0,2046].

// ---------------------------------------------------------------------------
// Kernel A: px lookup table (1 MB), computed once, reused by all 256 channels.
// ---------------------------------------------------------------------------
__global__ __launch_bounds__(256) void prep_px(float* __restrict__ pxbuf)
{
    const int n  = blockIdx.x * 256 + threadIdx.x;   // < NPIX
    const float cs = 50.0f / 255.5f;                    // R_MAX / (Hb/2 - 0.5)
    const float c1 = 2047.0f / 6.28318530717958647692f; // (Wr-1)/2pi
    const float c2 = 2047.0f / 2048.0f;                 // (Wr-1)/Wr
    const float y = ((float)(n >> 9)  - 255.5f) * cs;
    const float x = ((float)(n & 511) - 255.5f) * cs;
    float phi = atan2f(y, x);
    phi = (phi < 0.0f) ? phi + 6.28318530717958647692f : phi;
    pxbuf[n] = (2047.0f - phi * c1) * c2;               // in (0, 2046.01)
}

// ---------------------------------------------------------------------------
// Kernel B: one block = (channel, 16K-pixel tile). Stage averaged row in 8 KB
// LDS (single barrier), then free-run: coalesced px loads (L2-resident),
// LDS gathers, nontemporal stores. No channel loop, no barriers in the loop,
// low VGPR -> 32 waves/CU; waves drift out of phase so gather and store
// bursts overlap across waves instead of lockstepping.
// ---------------------------------------------------------------------------
__global__ __launch_bounds__(TPB) void sample_kernel(
    const float* __restrict__ rv,      // [B][C][Hr][Wr]
    const float* __restrict__ pxbuf,   // [NPIX]
    float* __restrict__ out)           // [BC][NPIX]
{
    __shared__ float row[Wr];          // 8 KB

    const int tile = blockIdx.x;       // 0..15
    const int ch   = blockIdx.y;       // 0..255
    const int tid  = threadIdx.x;

    // Stage averaged row: 512 f32x4, 128 threads -> 4 each, coalesced.
    {
        const float* chb = rv + (size_t)ch * (Hr * Wr) + (size_t)31 * Wr;
        const f32x4* r31 = (const f32x4*)chb;
        const f32x4* r32 = (const f32x4*)(chb + Wr);
        f32x4* dst = (f32x4*)row;
        #pragma unroll
        for (int q = 0; q < 4; ++q) {
            const int i = tid + q * TPB;
            dst[i] = r31[i] * 0.5f + r32[i] * 0.5f;
        }
    }
    __syncthreads();

    const f32x4* px4  = (const f32x4*)(pxbuf + (size_t)tile * T);
    f32x4*       out4 = (f32x4*)(out + (size_t)ch * NPIX + (size_t)tile * T);

    #pragma unroll 4
    for (int k = 0; k < T / 4 / TPB; ++k) {    // 32 iterations
        const int i = k * TPB + tid;
        const f32x4 p = px4[i];
        f32x4 r;
        #pragma unroll
        for (int j = 0; j < 4; ++j) {
            const int   xi = (int)p[j];        // p[j] >= 0: trunc == floor
            const float w  = p[j] - (float)xi;
            r[j] = row[xi] * (1.0f - w) + row[xi + 1] * w;
        }
        __builtin_nontemporal_store(r, out4 + i);
    }
}

extern "C" void kernel_launch(void* const* d_in, const int* in_sizes, int n_in,
                              void* d_out, int out_size, void* d_ws, size_t ws_size,
                              hipStream_t stream) {
    const float* rv_feat = (const float*)d_in[0];
    // d_in[1] (ref_bev) is unused by the reference computation.
    float* out = (float*)d_out;
    float* pxbuf = (float*)d_ws;       // NPIX floats = 1 MB of workspace

    prep_px<<<dim3(NPIX / 256), dim3(256), 0, stream>>>(pxbuf);
    sample_kernel<<<dim3(NT, BC), dim3(TPB), 0, stream>>>(rv_feat, pxbuf, out);
}

// Round 8
// 60.675 us; speedup vs baseline: 1.0359x; 1.0359x over previous
//
#include <hip/hip_runtime.h>
#include <math.h>

// Problem constants (from reference)
constexpr int Hr = 64;
constexpr int Wr = 2048;
constexpr int Hb = 512;
constexpr int Wb = 512;
constexpr int B  = 4;
constexpr int C  = 64;
constexpr int BC = B * C;            // 256 channels
constexpr int NPIX = Hb * Wb;        // 262144 pixels

constexpr int T = 8192;              // pixels per tile (per block)
constexpr int G = 8;                 // channels per block
constexpr int NTILE = NPIX / T;      // 32
constexpr int NCG   = BC / G;        // 32

typedef float f32x4 __attribute__((ext_vector_type(4)));
typedef int   i32x4 __attribute__((ext_vector_type(4)));

// py = 31.5 exactly -> rows 31,32 with wy = 0.5.
// px in float32 (identical arithmetic to R4/R6/R7 -> absmax 0.0156 << 0.066):
// bilinear interp is continuous in px; the phi-wrap discontinuity is ~0.64 px
// from the nearest sample, so float error cannot cross it. xi in [0,2046].

// ---------------------------------------------------------------------------
// Kernel A: px lookup tables (xi: int, w: float), one 4-pixel group/thread.
// 262K atan2f total (vs 8.4M when recomputed per block-of-8-channels).
// ---------------------------------------------------------------------------
__global__ __launch_bounds__(256) void prep_px(
    i32x4* __restrict__ xig,          // [NPIX/4]
    f32x4* __restrict__ wg)           // [NPIX/4]
{
    const int g  = blockIdx.x * 256 + threadIdx.x;   // group index < NPIX/4
    const float cs = 50.0f / 255.5f;                    // R_MAX / (Hb/2 - 0.5)
    const float c1 = 2047.0f / 6.28318530717958647692f; // (Wr-1)/2pi
    const float c2 = 2047.0f / 2048.0f;                 // (Wr-1)/Wr
    i32x4 xo; f32x4 wo;
    #pragma unroll
    for (int j = 0; j < 4; ++j) {
        const int n = g * 4 + j;
        const float y = ((float)(n >> 9)  - 255.5f) * cs;
        const float x = ((float)(n & 511) - 255.5f) * cs;
        float phi = atan2f(y, x);
        phi = (phi < 0.0f) ? phi + 6.28318530717958647692f : phi;
        const float px = (2047.0f - phi * c1) * c2;   // in (0, 2046.01)
        const int   xi = (int)px;                     // px >= 0: trunc == floor
        xo[j] = xi;
        wo[j] = px - (float)xi;
    }
    xig[g] = xo;
    wg[g]  = wo;
}

// ---------------------------------------------------------------------------
// Kernel B: R4 skeleton. One block = (8192-pixel tile, 8 channels). px data
// loaded ONCE into registers (coalesced), averaged rows double-buffered in
// LDS with issue-early/write-late staging; inner loop is 3 VALU + 1 ds_read2
// per sample.
// ---------------------------------------------------------------------------
__global__ __launch_bounds__(256) void rv2bev_main(
    const float* __restrict__ rv,     // [B][C][Hr][Wr]
    const i32x4* __restrict__ xig,    // [NPIX/4]
    const f32x4* __restrict__ wg,     // [NPIX/4]
    float* __restrict__ out)          // [BC][NPIX]
{
    __shared__ float rowbuf[2][Wr];   // 2 x 8 KB

    const int tile = blockIdx.x;      // 0..31
    const int cg   = blockIdx.y;      // 0..31
    const int tid  = threadIdx.x;

    // ---- px prologue: coalesced dwordx4 loads into registers ----
    int   xi[32];
    float w[32];
    {
        const i32x4* xs = xig + (size_t)tile * (T / 4);
        const f32x4* ws = wg  + (size_t)tile * (T / 4);
        #pragma unroll
        for (int k = 0; k < 8; ++k) {
            const int gidx = tid + k * 256;
            const i32x4 xv = xs[gidx];
            const f32x4 wv = ws[gidx];
            #pragma unroll
            for (int j = 0; j < 4; ++j) { xi[4 * k + j] = xv[j]; w[4 * k + j] = wv[j]; }
        }
    }

    // base of row 31, channel cg*G
    const float* rvb = rv + (size_t)(cg * G) * (Hr * Wr) + (size_t)31 * Wr;

    f32x4 sa0, sa1, sb0, sb1;         // staged rows for next channel

    // ---- prologue: stage channel 0 into rowbuf[0] ----
    {
        const f32x4* r31 = (const f32x4*)rvb;
        const f32x4* r32 = (const f32x4*)(rvb + Wr);
        sa0 = r31[tid]; sa1 = r31[tid + 256];
        sb0 = r32[tid]; sb1 = r32[tid + 256];
        f32x4* dst = (f32x4*)rowbuf[0];
        dst[tid]       = sa0 * 0.5f + sb0 * 0.5f;
        dst[tid + 256] = sa1 * 0.5f + sb1 * 0.5f;
    }

    for (int c = 0; c < G; ++c) {
        // issue-early: next channel's global loads before the barrier
        if (c + 1 < G) {
            const float* chb = rvb + (size_t)(c + 1) * (Hr * Wr);
            const f32x4* r31 = (const f32x4*)chb;
            const f32x4* r32 = (const f32x4*)(chb + Wr);
            sa0 = r31[tid]; sa1 = r31[tid + 256];
            sb0 = r32[tid]; sb1 = r32[tid + 256];
        }
        __syncthreads();              // rowbuf[c&1] staged & prior gathers done

        const float* __restrict__ row = rowbuf[c & 1];
        f32x4* out4 = (f32x4*)(out + (size_t)(cg * G + c) * NPIX + (size_t)tile * T);

        #pragma unroll
        for (int k = 0; k < 8; ++k) {
            f32x4 r;
            #pragma unroll
            for (int j = 0; j < 4; ++j) {
                const int i = k * 4 + j;
                const float a = row[xi[i]];
                const float b = row[xi[i] + 1];   // merges into ds_read2_b32
                r[j] = a + w[i] * (b - a);        // sub + fmac
            }
            __builtin_nontemporal_store(r, out4 + tid + k * 256);
        }

        // write-late: LDS write of next channel after this channel's gathers
        if (c + 1 < G) {
            f32x4* dst = (f32x4*)rowbuf[(c + 1) & 1];
            dst[tid]       = sa0 * 0.5f + sb0 * 0.5f;
            dst[tid + 256] = sa1 * 0.5f + sb1 * 0.5f;
        }
    }
}

extern "C" void kernel_launch(void* const* d_in, const int* in_sizes, int n_in,
                              void* d_out, int out_size, void* d_ws, size_t ws_size,
                              hipStream_t stream) {
    const float* rv_feat = (const float*)d_in[0];
    // d_in[1] (ref_bev) is unused by the reference computation.
    float* out = (float*)d_out;

    i32x4* xig = (i32x4*)d_ws;                         // NPIX/4 i32x4 = 1 MB
    f32x4* wg  = (f32x4*)((char*)d_ws + NPIX * 4);     // NPIX/4 f32x4 = 1 MB

    prep_px<<<dim3(NPIX / 4 / 256), dim3(256), 0, stream>>>(xig, wg);
    rv2bev_main<<<dim3(NTILE, NCG), dim3(256), 0, stream>>>(rv_feat, xig, wg, out);
}